// Round 2
// baseline (216.153 us; speedup 1.0000x reference)
//
#include <hip/hip_runtime.h>
#include <math.h>

#define IMG    224
#define NVIEWS 6
#define BATCH  16
#define NPTS   32768
#define PLANE  (IMG * IMG)       // 50176
#define HROWS  112               // half-plane tile
#define TILE_ELEMS (HROWS * IMG) // 25088 u32 = 100352 B dynamic LDS
#define NT     1024
#define NWAVES (NT / 64)         // 16
#define DCAP   2048              // dirty-entry list capacity (expected ~300)
#define NWG    (BATCH * NVIEWS * 2) // 192
#define KITERS (NPTS / (4 * NT))    // 8

typedef float fx4 __attribute__((ext_vector_type(4)));   // native vec for nontemporal

struct ViewTrig {
    float sa[NVIEWS], ca[NVIEWS], se[NVIEWS], ce[NVIEWS];
    float off0, off4;            // extreme splat offsets (footprint rectangle)
};

// fp32 ops with contraction OFF — these feed the pixel truncation and must
// round exactly like numpy's separate mul/add ufuncs.
__device__ __forceinline__ float fmul_(float a, float b) {
#pragma clang fp contract(off)
    return a * b;
}
__device__ __forceinline__ float fadd_(float a, float b) {
#pragma clang fp contract(off)
    return a + b;
}
__device__ __forceinline__ float fsub_(float a, float b) {
#pragma clang fp contract(off)
    return a - b;
}
// ((c + 1) * 0.5) * 223, truncate toward zero == astype(int32).
// (c+1)*0.5 is EXACT in fp32, so the two-step chain rounds exactly once on
// (c+1)*111.5 — identical to a single fmul by 111.5.
__device__ __forceinline__ int pix_(float c) {
    return (int)fmul_(fadd_(c, 1.0f), 111.5f);
}

// Order-preserving float->uint map (monotone over all finite floats).
// Any finite zf maps to a value > 0, so 0 is a safe "empty pixel" sentinel.
__device__ __forceinline__ unsigned fmap_(float f) {
    unsigned b = __float_as_uint(f);
    return b ^ ((unsigned)((int)b >> 31) | 0x80000000u);
}
__device__ __forceinline__ float fmap_inv_(unsigned u) {
    unsigned b = (u & 0x80000000u) ? (u ^ 0x80000000u) : ~u;
    return __uint_as_float(b);
}

__device__ __forceinline__ unsigned umax3_(unsigned a, unsigned b, unsigned c) {
    return max(max(a, b), c);
}

// ---------------------------------------------------------------------------
// Fused single-scan render, CENTER-SPLAT + EPILOGUE DILATION.
//
// The 5x5 splat offsets span 1.991 px per axis -> ~98% of hits cover an
// exact 3x3 pixel box centered at (x0i+1, y0i+1)  [span-3 <=> frac >= .0089;
// center = x0+1 needs frac >= .0035 -> 0.005 margin >> fp error].
// Scan: clean hits do ONE LDS atomicMax at the center (was 9 lane-atomics
// via the queue+drain path). Epilogue: each output pixel = 3x3 max-dilation
// of the tile (exact: dilation's boundary masking reproduces the clamped
// box; trunc-collapse near 0 can never be span-3, so it is always "dirty").
// Dirty hits (~4%: span-2 / center outside the half / x-border) go to a
// small LDS list and are applied AFTER the epilogue stores as global
// atomicMax on the float's uint pattern (all values >= 0 -> order-correct;
// same fmaf(zf,scale,bias) as the clean path -> bit-consistent).
// This removes the ballot/qcnt serialization and cuts scan LDS issues
// ~3.3 -> ~1.5 per point-group.
// ---------------------------------------------------------------------------
__global__ __launch_bounds__(NT, 4) void render_kernel(
    const float* __restrict__ pts, float* __restrict__ out, ViewTrig vt)
{
    extern __shared__ __align__(16) unsigned tile[];
    __shared__ uint2 dlist[DCAP];                   // 16 KB static
    __shared__ unsigned dcnt;
    __shared__ float smin[NWAVES], smax[NWAVES];

    // XCD-aware decode: xcd = bid&7 -> batches {xcd, xcd+8} pin to one XCD L2
    const int bid  = blockIdx.x;
    const int xcd  = bid & 7;
    const int slot = bid >> 3;            // 0..23
    const int hi   = (slot >= 12) ? 1 : 0;
    const int b    = xcd + 8 * hi;
    const int vh   = slot - 12 * hi;
    const int v    = vh >> 1;
    const int h    = vh & 1;
    const int bv   = b * NVIEWS + v;
    const int row0 = h * HROWS;
    const int row1 = row0 + HROWS - 1;

    const float sa = vt.sa[v], ca = vt.ca[v], se = vt.se[v], ce = vt.ce[v];
    const float off0 = vt.off0, off4 = vt.off4;
    const float4* p4 = (const float4*)(pts + (size_t)b * NPTS * 3);

    const int lane = threadIdx.x & 63;
    const int wave = threadIdx.x >> 6;
    const int tid  = threadIdx.x;

    // zero tile (b128 stores)
    {
        int4* t4 = (int4*)tile;
        for (int i = tid; i < TILE_ELEMS / 4; i += NT)
            t4[i] = make_int4(0, 0, 0, 0);
    }
    if (tid == 0) dcnt = 0;
    __syncthreads();

    float zmin = INFINITY, zmax = -INFINITY;

    auto do_point = [&](float x, float y, float z) {
        // strict fp32 chain -> pixel coordinates (bit-exact vs numpy)
        const float zr = fadd_(fmul_(x, sa), fmul_(z, ca));
        const float yr = fsub_(fmul_(y, ce), fmul_(zr, se));
        const float xr = fsub_(fmul_(x, ca), fmul_(z, sa));

        const int x0i = pix_(fadd_(xr, off0));
        const int x1i = pix_(fadd_(xr, off4));
        const int y0i = pix_(fadd_(yr, off0));
        const int y1i = pix_(fadd_(yr, off4));

        // relaxed depth (feeds minmax and the splat payload)
        const float zf = fmaf(zr, ce, y * se);
        zmin = fminf(zmin, zf);
        zmax = fmaxf(zmax, zf);

        const bool pred = (x1i >= 0) && (x0i <= IMG - 1) &&
                          (y1i >= row0) && (y0i <= row1);
        const int cxc = x0i + 1, cyc = y0i + 1;
        const bool clean = (x1i == x0i + 2) && (y1i == y0i + 2) &&
                           (cxc >= 0) && (cxc <= IMG - 1) &&
                           (cyc >= row0) && (cyc <= row1);   // clean => pred
        if (clean) {
            atomicMax(&tile[(cyc - row0) * IMG + cxc], fmap_(zf));
        } else if (pred) {
            const int cx0 = max(x0i, 0);
            const int cx1 = min(x1i, IMG - 1);
            const int cy0 = max(y0i, row0);
            const int cy1 = min(y1i, row1);
            const unsigned pk = (unsigned)cx0 | ((unsigned)cx1 << 8) |
                                ((unsigned)cy0 << 16) | ((unsigned)cy1 << 24);
            const unsigned di = atomicAdd(&dcnt, 1u);
            if (di < DCAP) dlist[di] = make_uint2(__float_as_uint(zf), pk);
        }
    };

    // Software-pipelined scan (loads for k+1 issued before body of k).
    float4 A = p4[3 * tid + 0];
    float4 B = p4[3 * tid + 1];
    float4 C = p4[3 * tid + 2];
    #pragma unroll
    for (int k = 0; k < KITERS; ++k) {
        float4 An, Bn, Cn;
        if (k + 1 < KITERS) {
            const int g = tid + (k + 1) * NT;
            An = p4[3 * g + 0];
            Bn = p4[3 * g + 1];
            Cn = p4[3 * g + 2];
        }
        do_point(A.x, A.y, A.z);
        do_point(A.w, B.x, B.y);
        do_point(B.z, B.w, C.x);
        do_point(C.y, C.z, C.w);
        if (k + 1 < KITERS) { A = An; B = Bn; C = Cn; }
    }

    // ---- block reduce zmin/zmax ----
    for (int o = 32; o > 0; o >>= 1) {
        zmin = fminf(zmin, __shfl_down(zmin, o, 64));
        zmax = fmaxf(zmax, __shfl_down(zmax, o, 64));
    }
    if (lane == 0) { smin[wave] = zmin; smax[wave] = zmax; }
    __syncthreads();   // also orders all LDS atomics before the epilogue
    if (threadIdx.x == 0) {
        float mn = smin[0], mx = smax[0];
        for (int w = 1; w < NWAVES; ++w) {
            mn = fminf(mn, smin[w]);
            mx = fmaxf(mx, smax[w]);
        }
        smin[0] = mn; smax[0] = mx;
    }
    __syncthreads();
    // feat = 0.3 + 0.7*(zf-zmin)/denom == zf*scale + bias  (err ~1e-6 << 2e-2)
    const float scale = 0.7f / ((smax[0] - smin[0]) + 1e-6f);
    const float bias  = 0.3f - smin[0] * scale;

    // ---- epilogue: 3x3 max-dilation of tile -> feat -> channels 0,1,2 ----
    // wave w owns local rows [7w, 7w+7): lane<56 handles cols [4*lane,4*lane+4)
    // vertical max of rows r-1,r,r+1 (masked at tile edges; the adjacent
    // half's rows are produced by its own WG), then horizontal max via
    // lane shuffles (lane<->col alignment makes row borders == lane borders).
    float* dst = out + ((size_t)bv * 3) * PLANE + (size_t)row0 * IMG;
    const uint4* src4 = (const uint4*)tile;
    const bool act = (lane < 56);
    const int c0 = lane * 4;
    for (int rr = 0; rr < 7; ++rr) {
        const int r = wave * 7 + rr;          // wave-uniform local row
        uint4 t0 = make_uint4(0u, 0u, 0u, 0u);
        uint4 t1 = t0, t2 = t0;
        if (act) {
            t1 = src4[r * 56 + lane];
            if (r > 0)          t0 = src4[(r - 1) * 56 + lane];
            if (r < HROWS - 1)  t2 = src4[(r + 1) * 56 + lane];
        }
        uint4 m;
        m.x = umax3_(t0.x, t1.x, t2.x);
        m.y = umax3_(t0.y, t1.y, t2.y);
        m.z = umax3_(t0.z, t1.z, t2.z);
        m.w = umax3_(t0.w, t1.w, t2.w);
        unsigned left  = __shfl_up(m.w, 1, 64);
        unsigned right = __shfl_down(m.x, 1, 64);
        if (lane == 0) left = 0u;             // col 0 border (lane==0 <=> c0==0)
        // lane 55's right comes from lane 56 whose m.x==0 -> col 223 border ok
        unsigned h0 = umax3_(left, m.x, m.y);
        unsigned h1 = umax3_(m.x, m.y, m.z);
        unsigned h2 = umax3_(m.y, m.z, m.w);
        unsigned h3 = umax3_(m.z, m.w, right);
        fx4 f;
        f.x = (h0 == 0u) ? 0.0f : fmaf(fmap_inv_(h0), scale, bias);
        f.y = (h1 == 0u) ? 0.0f : fmaf(fmap_inv_(h1), scale, bias);
        f.z = (h2 == 0u) ? 0.0f : fmaf(fmap_inv_(h2), scale, bias);
        f.w = (h3 == 0u) ? 0.0f : fmaf(fmap_inv_(h3), scale, bias);
        if (act) {
            #pragma unroll
            for (int c = 0; c < 3; ++c)
                __builtin_nontemporal_store(
                    f, (fx4*)(dst + (size_t)c * PLANE + (size_t)r * IMG + c0));
        }
    }

    // ---- dirty patch: exact boxes applied via global atomicMax ----
    __threadfence();        // drain this thread's stores to L2
    __syncthreads();        // all stores visible before any patch atomic
    const unsigned nd = min(dcnt, (unsigned)DCAP);
    unsigned* outu = (unsigned*)(out + ((size_t)bv * 3) * PLANE);
    for (unsigned j = tid; j < nd * 3u; j += NT) {
        const uint2 e = dlist[j / 3u];
        const int rsl = (int)(j % 3u);
        const int cx0 = (int)(e.y & 255u);
        const int cx1 = (int)((e.y >> 8) & 255u);
        const int r0g = (int)((e.y >> 16) & 255u);
        const int r1g = (int)(e.y >> 24);
        const int r = r0g + rsl;
        if (r > r1g) continue;
        const float feat = fmaf(__uint_as_float(e.x), scale, bias);
        const unsigned fu = __float_as_uint(feat);   // >0; uint cmp == float cmp
        #pragma unroll
        for (int dx = 0; dx < 3; ++dx) {
            const int cx = cx0 + dx;
            if (cx <= cx1) {
                #pragma unroll
                for (int c = 0; c < 3; ++c)
                    atomicMax(outu + (size_t)c * PLANE + (size_t)r * IMG + cx, fu);
            }
        }
    }
}

extern "C" void kernel_launch(void* const* d_in, const int* in_sizes, int n_in,
                              void* d_out, int out_size, void* d_ws, size_t ws_size,
                              hipStream_t stream)
{
    const float* pts = (const float*)d_in[0];
    float* out = (float*)d_out;

    // fp32-faithful constants (JAX x32 semantics), same as the passing rounds.
    ViewTrig vt;
    const float d2r = (float)(M_PI / 180.0);
    const float el_deg[NVIEWS] = {0.0f, 30.0f, -30.0f, 0.0f, 0.0f, 0.0f};
    for (int v = 0; v < NVIEWS; ++v) {
        float a = (float)(60 * v) * d2r;
        float e = el_deg[v] * d2r;
        vt.sa[v] = (float)sin((double)a);
        vt.ca[v] = (float)cos((double)a);
        vt.se[v] = (float)sin((double)e);
        vt.ce[v] = (float)cos((double)e);
    }
    {
        const float s = (float)(2.0 / 224.0);  // linspace end points, exact in fp32
        vt.off0 = -s;
        vt.off4 = s;
    }

    // Opt in to >64KB dynamic LDS (160 KiB/CU on gfx950). Graph-capture safe.
    (void)hipFuncSetAttribute(reinterpret_cast<const void*>(render_kernel),
                              hipFuncAttributeMaxDynamicSharedMemorySize,
                              TILE_ELEMS * (int)sizeof(int));

    render_kernel<<<NWG, NT, TILE_ELEMS * sizeof(int), stream>>>(pts, out, vt);
}

// Round 3
// 91.978 us; speedup vs baseline: 2.3501x; 2.3501x over previous
//
#include <hip/hip_runtime.h>
#include <math.h>

#define IMG    224
#define NVIEWS 6
#define BATCH  16
#define NPTS   32768
#define PLANE  (IMG * IMG)       // 50176
#define HROWS  112               // half-plane tile
#define TILE_ELEMS (HROWS * IMG) // 25088 u32 = 100352 B dynamic LDS
#define NT     1024
#define NWAVES (NT / 64)         // 16
#define DCAP   2048              // dirty-entry list capacity (expected ~400)
#define NWG    (BATCH * NVIEWS * 2) // 192
#define KITERS (NPTS / (4 * NT))    // 8

typedef float fx4 __attribute__((ext_vector_type(4)));   // native vec for nontemporal

struct ViewTrig {
    float sa[NVIEWS], ca[NVIEWS], se[NVIEWS], ce[NVIEWS];
    float off0, off4;            // extreme splat offsets (footprint rectangle)
};

// fp32 ops with contraction OFF — these feed the pixel truncation and must
// round exactly like numpy's separate mul/add ufuncs.
__device__ __forceinline__ float fmul_(float a, float b) {
#pragma clang fp contract(off)
    return a * b;
}
__device__ __forceinline__ float fadd_(float a, float b) {
#pragma clang fp contract(off)
    return a + b;
}
__device__ __forceinline__ float fsub_(float a, float b) {
#pragma clang fp contract(off)
    return a - b;
}
// ((c + 1) * 0.5) * 223, truncate toward zero == astype(int32).
// (c+1)*0.5 is EXACT in fp32, so the two-step chain rounds exactly once on
// (c+1)*111.5 — identical to a single fmul by 111.5.
__device__ __forceinline__ int pix_(float c) {
    return (int)fmul_(fadd_(c, 1.0f), 111.5f);
}

// Order-preserving float->uint map (monotone over all finite floats).
// Any finite zf maps to a value > 0, so 0 is a safe "empty pixel" sentinel.
__device__ __forceinline__ unsigned fmap_(float f) {
    unsigned b = __float_as_uint(f);
    return b ^ ((unsigned)((int)b >> 31) | 0x80000000u);
}
__device__ __forceinline__ float fmap_inv_(unsigned u) {
    unsigned b = (u & 0x80000000u) ? (u ^ 0x80000000u) : ~u;
    return __uint_as_float(b);
}

__device__ __forceinline__ unsigned umax3_(unsigned a, unsigned b, unsigned c) {
    return max(max(a, b), c);
}

// ---------------------------------------------------------------------------
// Fused single-scan render, CENTER-SPLAT + EPILOGUE DILATION, all-LDS.
//
// ~97% of hits cover an exact 3x3 box centered at (x0i+1, y0i+1); those do
// ONE LDS atomicMax at the center, and the epilogue reconstructs the box via
// a 3x3 max-dilation (boundary masking == the clamped box; cross-half
// boundary contributions are covered by the neighbor WG's dirty path).
// Dirty hits (span-2 / center outside this half / x-border) go to an LDS
// list as exact boxes.
//
// Round-2 post-mortem: resolving dirty entries with global atomicMax +
// __threadfence was a disaster (threadfence = buffer_wbl2 full-L2 writeback
// per WG on non-coherent-XCD gfx950; +30MB HBM writes; ~1.5M fabric-scope
// atomic RMWs) -> 154us with everything idle. This version resolves dirty
// entries IN LDS: dilation results are parked in registers (hreg[7][4],
// static-indexed), the tile is zeroed and reused as a dirty overlay
// (exact boxes, LDS atomicMax), and the final pixel is
// max(dilated, overlay) converted once and stored non-temporally.
// No global atomics, no threadfence anywhere.
// ---------------------------------------------------------------------------
__global__ __launch_bounds__(NT, 4) void render_kernel(
    const float* __restrict__ pts, float* __restrict__ out, ViewTrig vt)
{
    extern __shared__ __align__(16) unsigned tile[];
    __shared__ uint2 dlist[DCAP];                   // 16 KB static
    __shared__ unsigned dcnt;
    __shared__ float smin[NWAVES], smax[NWAVES];

    // XCD-aware decode: xcd = bid&7 -> batches {xcd, xcd+8} pin to one XCD L2
    const int bid  = blockIdx.x;
    const int xcd  = bid & 7;
    const int slot = bid >> 3;            // 0..23
    const int hi   = (slot >= 12) ? 1 : 0;
    const int b    = xcd + 8 * hi;
    const int vh   = slot - 12 * hi;
    const int v    = vh >> 1;
    const int h    = vh & 1;
    const int bv   = b * NVIEWS + v;
    const int row0 = h * HROWS;
    const int row1 = row0 + HROWS - 1;

    const float sa = vt.sa[v], ca = vt.ca[v], se = vt.se[v], ce = vt.ce[v];
    const float off0 = vt.off0, off4 = vt.off4;
    const float4* p4 = (const float4*)(pts + (size_t)b * NPTS * 3);

    const int lane = threadIdx.x & 63;
    const int wave = threadIdx.x >> 6;
    const int tid  = threadIdx.x;

    // zero tile (b128 stores)
    {
        int4* t4 = (int4*)tile;
        for (int i = tid; i < TILE_ELEMS / 4; i += NT)
            t4[i] = make_int4(0, 0, 0, 0);
    }
    if (tid == 0) dcnt = 0;
    __syncthreads();

    float zmin = INFINITY, zmax = -INFINITY;

    auto do_point = [&](float x, float y, float z) {
        // strict fp32 chain -> pixel coordinates (bit-exact vs numpy)
        const float zr = fadd_(fmul_(x, sa), fmul_(z, ca));
        const float yr = fsub_(fmul_(y, ce), fmul_(zr, se));
        const float xr = fsub_(fmul_(x, ca), fmul_(z, sa));

        const int x0i = pix_(fadd_(xr, off0));
        const int x1i = pix_(fadd_(xr, off4));
        const int y0i = pix_(fadd_(yr, off0));
        const int y1i = pix_(fadd_(yr, off4));

        // relaxed depth (feeds minmax and the splat payload)
        const float zf = fmaf(zr, ce, y * se);
        zmin = fminf(zmin, zf);
        zmax = fmaxf(zmax, zf);

        const bool pred = (x1i >= 0) && (x0i <= IMG - 1) &&
                          (y1i >= row0) && (y0i <= row1);
        const int cxc = x0i + 1, cyc = y0i + 1;
        const bool clean = (x1i == x0i + 2) && (y1i == y0i + 2) &&
                           (cxc >= 0) && (cxc <= IMG - 1) &&
                           (cyc >= row0) && (cyc <= row1);   // clean => pred
        if (clean) {
            atomicMax(&tile[(cyc - row0) * IMG + cxc], fmap_(zf));
        } else if (pred) {
            const int cx0 = max(x0i, 0);
            const int cx1 = min(x1i, IMG - 1);
            const int cy0 = max(y0i, row0);
            const int cy1 = min(y1i, row1);
            const unsigned pk = (unsigned)cx0 | ((unsigned)cx1 << 8) |
                                ((unsigned)cy0 << 16) | ((unsigned)cy1 << 24);
            const unsigned di = atomicAdd(&dcnt, 1u);
            if (di < DCAP) dlist[di] = make_uint2(fmap_(zf), pk);
        }
    };

    // Software-pipelined scan (loads for k+1 issued before body of k).
    float4 A = p4[3 * tid + 0];
    float4 B = p4[3 * tid + 1];
    float4 C = p4[3 * tid + 2];
    #pragma unroll
    for (int k = 0; k < KITERS; ++k) {
        float4 An, Bn, Cn;
        if (k + 1 < KITERS) {
            const int g = tid + (k + 1) * NT;
            An = p4[3 * g + 0];
            Bn = p4[3 * g + 1];
            Cn = p4[3 * g + 2];
        }
        do_point(A.x, A.y, A.z);
        do_point(A.w, B.x, B.y);
        do_point(B.z, B.w, C.x);
        do_point(C.y, C.z, C.w);
        if (k + 1 < KITERS) { A = An; B = Bn; C = Cn; }
    }

    // ---- block reduce zmin/zmax ----
    for (int o = 32; o > 0; o >>= 1) {
        zmin = fminf(zmin, __shfl_down(zmin, o, 64));
        zmax = fmaxf(zmax, __shfl_down(zmax, o, 64));
    }
    if (lane == 0) { smin[wave] = zmin; smax[wave] = zmax; }
    __syncthreads();   // also orders all LDS atomics before the epilogue
    if (threadIdx.x == 0) {
        float mn = smin[0], mx = smax[0];
        for (int w = 1; w < NWAVES; ++w) {
            mn = fminf(mn, smin[w]);
            mx = fmaxf(mx, smax[w]);
        }
        smin[0] = mn; smax[0] = mx;
    }
    __syncthreads();
    // feat = 0.3 + 0.7*(zf-zmin)/denom == zf*scale + bias  (err ~1e-6 << 2e-2)
    const float scale = 0.7f / ((smax[0] - smin[0]) + 1e-6f);
    const float bias  = 0.3f - smin[0] * scale;

    // ---- epilogue phase 1: 3x3 max-dilation of tile -> registers ----
    // wave w owns local rows [7w, 7w+7); lane<56 handles cols [4*lane,4*lane+4).
    // Vertical max of rows r-1,r,r+1 (masked at tile edges), then horizontal
    // max via lane shuffles. Results parked in hreg[7][4] (static indexing).
    const uint4* src4 = (const uint4*)tile;
    const bool act = (lane < 56);
    const int c0 = lane * 4;
    unsigned hreg[7][4];
    #pragma unroll
    for (int rr = 0; rr < 7; ++rr) {
        const int r = wave * 7 + rr;          // wave-uniform local row
        uint4 t0 = make_uint4(0u, 0u, 0u, 0u);
        uint4 t1 = t0, t2 = t0;
        if (act) {
            t1 = src4[r * 56 + lane];
            if (r > 0)          t0 = src4[(r - 1) * 56 + lane];
            if (r < HROWS - 1)  t2 = src4[(r + 1) * 56 + lane];
        }
        uint4 m;
        m.x = umax3_(t0.x, t1.x, t2.x);
        m.y = umax3_(t0.y, t1.y, t2.y);
        m.z = umax3_(t0.z, t1.z, t2.z);
        m.w = umax3_(t0.w, t1.w, t2.w);
        unsigned left  = __shfl_up(m.w, 1, 64);
        unsigned right = __shfl_down(m.x, 1, 64);
        if (lane == 0) left = 0u;             // col 0 border (lane==0 <=> c0==0)
        // lane 55's right comes from lane 56 whose m.x==0 -> col 223 border ok
        hreg[rr][0] = umax3_(left, m.x, m.y);
        hreg[rr][1] = umax3_(m.x, m.y, m.z);
        hreg[rr][2] = umax3_(m.y, m.z, m.w);
        hreg[rr][3] = umax3_(m.z, m.w, right);
    }
    __syncthreads();          // all dilation reads of tile complete

    // ---- epilogue phase 2: tile becomes the dirty overlay ----
    {
        int4* t4 = (int4*)tile;
        for (int i = tid; i < TILE_ELEMS / 4; i += NT)
            t4[i] = make_int4(0, 0, 0, 0);
    }
    __syncthreads();          // tile cleared
    const unsigned nd = min(dcnt, (unsigned)DCAP);
    for (unsigned j = tid; j < nd * 3u; j += NT) {
        const uint2 e = dlist[j / 3u];
        const int rsl = (int)(j % 3u);
        const int cx0 = (int)(e.y & 255u);
        const int cx1 = (int)((e.y >> 8) & 255u);
        const int r0g = (int)((e.y >> 16) & 255u);
        const int r1g = (int)(e.y >> 24);
        const int r = r0g + rsl;
        if (r > r1g) continue;
        unsigned* rowp = &tile[(r - row0) * IMG];
        #pragma unroll
        for (int dx = 0; dx < 3; ++dx) {
            const int cx = cx0 + dx;
            if (cx <= cx1) atomicMax(rowp + cx, e.x);
        }
    }
    __syncthreads();          // overlay complete

    // ---- epilogue phase 3: max(dilated, overlay) -> feat -> 3 channels ----
    float* dst = out + ((size_t)bv * 3) * PLANE + (size_t)row0 * IMG;
    #pragma unroll
    for (int rr = 0; rr < 7; ++rr) {
        const int r = wave * 7 + rr;
        uint4 o = make_uint4(0u, 0u, 0u, 0u);
        if (act) o = src4[r * 56 + lane];
        const unsigned h0 = max(hreg[rr][0], o.x);
        const unsigned h1 = max(hreg[rr][1], o.y);
        const unsigned h2 = max(hreg[rr][2], o.z);
        const unsigned h3 = max(hreg[rr][3], o.w);
        fx4 f;
        f.x = (h0 == 0u) ? 0.0f : fmaf(fmap_inv_(h0), scale, bias);
        f.y = (h1 == 0u) ? 0.0f : fmaf(fmap_inv_(h1), scale, bias);
        f.z = (h2 == 0u) ? 0.0f : fmaf(fmap_inv_(h2), scale, bias);
        f.w = (h3 == 0u) ? 0.0f : fmaf(fmap_inv_(h3), scale, bias);
        if (act) {
            #pragma unroll
            for (int c = 0; c < 3; ++c)
                __builtin_nontemporal_store(
                    f, (fx4*)(dst + (size_t)c * PLANE + (size_t)r * IMG + c0));
        }
    }
}

extern "C" void kernel_launch(void* const* d_in, const int* in_sizes, int n_in,
                              void* d_out, int out_size, void* d_ws, size_t ws_size,
                              hipStream_t stream)
{
    const float* pts = (const float*)d_in[0];
    float* out = (float*)d_out;

    // fp32-faithful constants (JAX x32 semantics), same as the passing rounds.
    ViewTrig vt;
    const float d2r = (float)(M_PI / 180.0);
    const float el_deg[NVIEWS] = {0.0f, 30.0f, -30.0f, 0.0f, 0.0f, 0.0f};
    for (int v = 0; v < NVIEWS; ++v) {
        float a = (float)(60 * v) * d2r;
        float e = el_deg[v] * d2r;
        vt.sa[v] = (float)sin((double)a);
        vt.ca[v] = (float)cos((double)a);
        vt.se[v] = (float)sin((double)e);
        vt.ce[v] = (float)cos((double)e);
    }
    {
        const float s = (float)(2.0 / 224.0);  // linspace end points, exact in fp32
        vt.off0 = -s;
        vt.off4 = s;
    }

    // Opt in to >64KB dynamic LDS (160 KiB/CU on gfx950). Graph-capture safe.
    (void)hipFuncSetAttribute(reinterpret_cast<const void*>(render_kernel),
                              hipFuncAttributeMaxDynamicSharedMemorySize,
                              TILE_ELEMS * (int)sizeof(int));

    render_kernel<<<NWG, NT, TILE_ELEMS * sizeof(int), stream>>>(pts, out, vt);
}